// Round 6
// baseline (7539.858 us; speedup 1.0000x reference)
//
#include <hip/hip_runtime.h>
#include <math.h>

#define NN   16384   // nodes
#define DD   512     // feature dim
#define KNN  16      // neighbors
#define MT   64      // rows per block
#define CT   128     // cols per tile
#define KT   32      // k-slab staged in LDS
#define SIM_LD 132   // sim row stride (16B-aligned, breaks pow2)

// ---- Pass 0: row norms, bit-exact replica of np.linalg.norm(axis=-1) -------
// numpy FLOAT_pairwise_sum, NPY_SIMD base case at wheel baseline SSE3
// (npyv_nlanes_f32 = 4). Per 128-elem block:
//   r_m[j] (m,j in 0..3) = sum_{t=0..7} s[16t + 4m + j]   (ascending t,
//       init-by-load == 0+x bitwise), s[i] = fl(x[i]*x[i]) (no FMA)
//   v[j] = (r0[j]+r1[j]) + (r2[j]+r3[j])
//   B    = (v0+v1) + (v2+v3)          (two _mm_hadd_ps)
// Recursion for n=512: total = (B0+B1)+(B2+B3).
__global__ __launch_bounds__(256) void norm_kernel(const float* __restrict__ feat,
                                                   float* __restrict__ nrm) {
#pragma clang fp contract(off)
    const int t   = threadIdx.x;
    const int row = blockIdx.x * 64 + (t >> 2);
    const int bid = t & 3;                      // which 128-elem block
    const float4* p4 = (const float4*)(feat + (size_t)row * DD + bid * 128);

    float r[4][4];                              // r[m][j]
    #pragma unroll
    for (int m = 0; m < 4; m++) {               // t = 0: elements 4m+j
        float4 q = p4[m];
        r[m][0] = q.x * q.x; r[m][1] = q.y * q.y;
        r[m][2] = q.z * q.z; r[m][3] = q.w * q.w;
    }
    #pragma unroll
    for (int tt = 1; tt < 8; tt++) {            // elements 16*tt + 4m + j
        #pragma unroll
        for (int m = 0; m < 4; m++) {
            float4 q = p4[tt * 4 + m];
            r[m][0] += q.x * q.x; r[m][1] += q.y * q.y;
            r[m][2] += q.z * q.z; r[m][3] += q.w * q.w;
        }
    }
    float v0 = (r[0][0] + r[1][0]) + (r[2][0] + r[3][0]);
    float v1 = (r[0][1] + r[1][1]) + (r[2][1] + r[3][1]);
    float v2 = (r[0][2] + r[1][2]) + (r[2][2] + r[3][2]);
    float v3 = (r[0][3] + r[1][3]) + (r[2][3] + r[3][3]);
    float B  = (v0 + v1) + (v2 + v3);           // hadd,hadd
    // IEEE add commutes bitwise -> xor-shuffle combine == (B0+B1)+(B2+B3)
    B += __shfl_xor(B, 1, 64);
    B += __shfl_xor(B, 2, 64);
    // HIP sqrtf is correctly-rounded fp32 (default opts) == numpy sqrt
    if (bid == 0) nrm[row] = sqrtf(B) + 1e-10f;  // +1e-10f: bitwise no-op, kept for fidelity
}

// ---- Pass 0b: fn = feature / nrm, IEEE-CR fp32 division --------------------
__global__ __launch_bounds__(256) void fn_kernel(const float* __restrict__ feat,
                                                 const float* __restrict__ nrm,
                                                 float* __restrict__ fn) {
    int i4  = blockIdx.x * 256 + threadIdx.x;   // float4 index
    int row = i4 >> 7;                          // 128 float4 per row
    float n = nrm[row];
    float4 v = ((const float4*)feat)[i4];
    ((float4*)fn)[i4] = make_float4(v.x / n, v.y / n, v.z / n, v.w / n);
}

// ---- Pass 1: fused GEMM + top-16.  Reference GEMM = numpy noblas matmul:
// one accumulator per C element, single ascending-k FMA chain over all 512
// (NO K-split — R2/R4/R5 vs R3 evidence).
template <bool PRE>
__global__ __launch_bounds__(256) void knn_kernel(const float* __restrict__ src,
                                                  const float* __restrict__ nrm,
                                                  int* __restrict__ out) {
    __shared__ union {
        struct { float As[KT][MT]; float Bs[KT][CT]; } stage;  // 24.0 KB
        float sim[MT][SIM_LD];                                 // 33.8 KB
    } u;
    __shared__ float tval[MT][KNN];  // sorted descending
    __shared__ int   tidx[MT][KNN];

    const int t  = threadIdx.x;
    const int r0 = blockIdx.x * MT;
    const int tx = t & 15;
    const int ty = t >> 4;

    for (int i = t; i < MT * KNN; i += 256) {
        ((float*)tval)[i] = -3.4e38f;
        ((int*)tidx)[i]   = 0;
    }

    const int arow = t >> 2, akq = t & 3;   // A: 64 rows x 4 k-octets
    const int bcol = t >> 1, bkh = t & 1;   // B: 128 cols x 2 k-halves

    for (int ct = 0; ct < NN / CT; ct++) {
        const int c0 = ct * CT;
        float acc[4][8];
        #pragma unroll
        for (int rr = 0; rr < 4; rr++)
            #pragma unroll
            for (int cc = 0; cc < 8; cc++) acc[rr][cc] = 0.0f;

        for (int kt = 0; kt < DD / KT; kt++) {
            const int kb = kt * KT;
            __syncthreads();  // previous users of union done (compute/merge)

            {   // stage A: 64x32 -> As[k][row], normalized
                const float* ap = src + (size_t)(r0 + arow) * DD + kb + akq * 8;
                float4 a0 = *(const float4*)ap;
                float4 a1 = *(const float4*)(ap + 4);
                if (!PRE) {
                    float nA = nrm[r0 + arow];
                    a0.x /= nA; a0.y /= nA; a0.z /= nA; a0.w /= nA;
                    a1.x /= nA; a1.y /= nA; a1.z /= nA; a1.w /= nA;
                }
                int k0 = akq * 8;
                u.stage.As[k0 + 0][arow] = a0.x; u.stage.As[k0 + 1][arow] = a0.y;
                u.stage.As[k0 + 2][arow] = a0.z; u.stage.As[k0 + 3][arow] = a0.w;
                u.stage.As[k0 + 4][arow] = a1.x; u.stage.As[k0 + 5][arow] = a1.y;
                u.stage.As[k0 + 6][arow] = a1.z; u.stage.As[k0 + 7][arow] = a1.w;
            }
            {   // stage B: 128x32 -> Bs[k][col], normalized
                const float* bp = src + (size_t)(c0 + bcol) * DD + kb + bkh * 16;
                float4 b0 = *(const float4*)bp;
                float4 b1 = *(const float4*)(bp + 4);
                float4 b2 = *(const float4*)(bp + 8);
                float4 b3 = *(const float4*)(bp + 12);
                if (!PRE) {
                    float nB = nrm[c0 + bcol];
                    b0.x /= nB; b0.y /= nB; b0.z /= nB; b0.w /= nB;
                    b1.x /= nB; b1.y /= nB; b1.z /= nB; b1.w /= nB;
                    b2.x /= nB; b2.y /= nB; b2.z /= nB; b2.w /= nB;
                    b3.x /= nB; b3.y /= nB; b3.z /= nB; b3.w /= nB;
                }
                int k0 = bkh * 16;
                u.stage.Bs[k0 +  0][bcol] = b0.x; u.stage.Bs[k0 +  1][bcol] = b0.y;
                u.stage.Bs[k0 +  2][bcol] = b0.z; u.stage.Bs[k0 +  3][bcol] = b0.w;
                u.stage.Bs[k0 +  4][bcol] = b1.x; u.stage.Bs[k0 +  5][bcol] = b1.y;
                u.stage.Bs[k0 +  6][bcol] = b1.z; u.stage.Bs[k0 +  7][bcol] = b1.w;
                u.stage.Bs[k0 +  8][bcol] = b2.x; u.stage.Bs[k0 +  9][bcol] = b2.y;
                u.stage.Bs[k0 + 10][bcol] = b2.z; u.stage.Bs[k0 + 11][bcol] = b2.w;
                u.stage.Bs[k0 + 12][bcol] = b3.x; u.stage.Bs[k0 + 13][bcol] = b3.y;
                u.stage.Bs[k0 + 14][bcol] = b3.z; u.stage.Bs[k0 + 15][bcol] = b3.w;
            }
            __syncthreads();

            // single ascending-k FMA chain, one accumulator per C element
            #pragma unroll
            for (int kk = 0; kk < KT; kk++) {
                float4 av  = *(const float4*)&u.stage.As[kk][ty * 4];
                float4 bv0 = *(const float4*)&u.stage.Bs[kk][tx * 4];
                float4 bv1 = *(const float4*)&u.stage.Bs[kk][64 + tx * 4];
                float ar[4] = {av.x, av.y, av.z, av.w};
                float br[8] = {bv0.x, bv0.y, bv0.z, bv0.w,
                               bv1.x, bv1.y, bv1.z, bv1.w};
                #pragma unroll
                for (int rr = 0; rr < 4; rr++)
                    #pragma unroll
                    for (int cc = 0; cc < 8; cc++)
                        acc[rr][cc] = __builtin_fmaf(ar[rr], br[cc], acc[rr][cc]);
            }
        }
        __syncthreads();  // As/Bs reads done before sim overwrites union

        {   // park 64x128 sim tile
            #pragma unroll
            for (int rr = 0; rr < 4; rr++) {
                *(float4*)&u.sim[ty * 4 + rr][tx * 4] =
                    make_float4(acc[rr][0], acc[rr][1], acc[rr][2], acc[rr][3]);
                *(float4*)&u.sim[ty * 4 + rr][64 + tx * 4] =
                    make_float4(acc[rr][4], acc[rr][5], acc[rr][6], acc[rr][7]);
            }
        }
        __syncthreads();

        // streaming top-16 merge; one thread per row spread across 4 waves.
        // strict '>' == jax.lax.top_k stable tie-break (lower index wins).
        if ((t & 3) == 0) {
            const int lr = t >> 2, grow = r0 + lr;
            float vmin = tval[lr][KNN - 1];
            for (int j = 0; j < CT / 4; j++) {
                float4 v4 = *(const float4*)&u.sim[lr][j * 4];
                float vs[4] = {v4.x, v4.y, v4.z, v4.w};
                #pragma unroll
                for (int e = 0; e < 4; e++) {
                    int c = c0 + j * 4 + e;
                    float v = vs[e];
                    if (c == grow) continue;   // zeroed diag never in top-16
                    if (v > vmin) {
                        int p = KNN - 1;
                        while (p > 0 && tval[lr][p - 1] < v) {
                            tval[lr][p] = tval[lr][p - 1];
                            tidx[lr][p] = tidx[lr][p - 1];
                            p--;
                        }
                        tval[lr][p] = v;
                        tidx[lr][p] = c;
                        vmin = tval[lr][KNN - 1];
                    }
                }
            }
        }
        // next iteration's first __syncthreads fences merge vs restage
    }

    __syncthreads();
    for (int i = t; i < MT * KNN; i += 256) {
        int lr = i / KNN, j = i % KNN;
        int grow = r0 + lr;
        out[(size_t)grow * KNN + j]            = grow;
        out[(size_t)NN * KNN + grow * KNN + j] = tidx[lr][j];
    }
}

extern "C" void kernel_launch(void* const* d_in, const int* in_sizes, int n_in,
                              void* d_out, int out_size, void* d_ws, size_t ws_size,
                              hipStream_t stream) {
    const float* feat = (const float*)d_in[0];
    float* nrm = (float*)d_ws;                         // 64 KB
    int*   out = (int*)d_out;                          // int32 (jax demotes int64)

    norm_kernel<<<NN / 64, 256, 0, stream>>>(feat, nrm);

    const size_t need = 64 * 1024 + (size_t)NN * DD * sizeof(float);  // nrm + fn
    if (ws_size >= need) {
        float* fn = (float*)((char*)d_ws + 64 * 1024); // 32 MB normalized copy
        fn_kernel<<<(NN * DD / 4) / 256, 256, 0, stream>>>(feat, nrm, fn);
        knn_kernel<true><<<NN / MT, 256, 0, stream>>>(fn, nrm, out);
    } else {
        // divide during staging (bitwise-identical IEEE div, just redundant)
        knn_kernel<false><<<NN / MT, 256, 0, stream>>>(feat, nrm, out);
    }
}